// Round 12
// baseline (255.156 us; speedup 1.0000x reference)
//
#include <hip/hip_runtime.h>
#include <cstdint>

#define M_PTS 8192
#define N_QRY 8192
#define BATCH 4

typedef unsigned long long ull;

// ---------------- helpers ----------------
__device__ __forceinline__ float d2_exact(float qx, float qy, float qz, float q2, float4 p) {
#pragma clang fp contract(off)
  float dot = (qx * p.x + qy * p.y) + qz * p.z;   // reference op order, no fma
  return (q2 + p.w) - 2.0f * dot;
}

__device__ __forceinline__ unsigned flipf(float d) {
  unsigned u = __float_as_uint(d);
  return u ^ ((unsigned)((int)u >> 31) | 0x80000000u);   // order-preserving float->uint
}

__device__ __forceinline__ int lane_prefix(unsigned long long m) {
  return __builtin_amdgcn_mbcnt_hi((unsigned)(m >> 32),
         __builtin_amdgcn_mbcnt_lo((unsigned)m, 0));
}

__device__ __forceinline__ void ld_lds16(const float4* g, float4* l) {
  __builtin_amdgcn_global_load_lds((const __attribute__((address_space(1))) void*)g,
                                   (__attribute__((address_space(3))) void*)l, 16, 0, 0);
}

// Upper bound on the 16th-smallest of the 64 per-lane mins, via ballot bisection.
// Invariant: count(mn <= hi) >= 16 holds from init (hi = wave max -> 64). 10 steps
// give resolution (hi0-lo0)/1024; looseness only ADDS candidates, never drops one.
__device__ __forceinline__ float tau16(float mn) {
  float lo = mn, hi = mn;
#pragma unroll
  for (int j = 1; j < 64; j <<= 1) {
    lo = fminf(lo, __shfl_xor(lo, j));
    hi = fmaxf(hi, __shfl_xor(hi, j));
  }
#pragma unroll
  for (int it = 0; it < 10; it++) {
    float mid = 0.5f * (lo + hi);
    int cnt = __popcll(__ballot(mn <= mid));
    if (cnt >= 16) hi = mid; else lo = mid;   // wave-uniform
  }
  return hi;
}

// Full 64-lane ascending bitonic sort of u64 keys; lane i ends with the i-th
// smallest. Same network/orientation as the R0-verified rank16.
__device__ __forceinline__ ull bsort64(ull v, int lane) {
#pragma unroll
  for (int k = 2; k <= 64; k <<= 1) {
#pragma unroll
    for (int j = k >> 1; j >= 1; j >>= 1) {
      ull o = __shfl_xor(v, j);
      bool keepmin = (((lane & k) == 0) == ((lane & j) == 0));
      ull lo = v < o ? v : o;
      ull hi = v < o ? o : v;
      v = keepmin ? lo : hi;
    }
  }
  return v;
}

// ---------------- K0: fused prep (pack orig + pack query + transpose lf) ----------
// blocks [0,128): pack original_pts -> pp ; [128,256): pack query_pts -> qp ;
// [256,768): transpose local_feat (B,64,M) -> (B,M,64).
__global__ void prep_kernel(const float* __restrict__ original_pts,
                            const float* __restrict__ query_pts,
                            const float* __restrict__ lf,
                            float4* __restrict__ pp, float4* __restrict__ qp,
                            float* __restrict__ lfT) {
#pragma clang fp contract(off)
  const int bid = blockIdx.x;
  if (bid < 256) {
    const float* src = (bid < 128) ? original_pts : query_pts;
    float4* dst = (bid < 128) ? pp : qp;
    int i = (bid & 127) * 256 + threadIdx.x;     // < 32768
    int b = i >> 13, m = i & (M_PTS - 1);
    const float* s = src + (size_t)b * 3 * M_PTS;
    float x = s[m], y = s[M_PTS + m], z = s[2 * M_PTS + m];
    float ss = (x * x + y * y) + z * z;   // matches jnp.sum(pts**2, axis=1) order
    dst[i] = make_float4(x, y, z, ss);
    return;
  }
  __shared__ float tile[64][65];
  int vbid = bid - 256;
  int bb = vbid >> 7;
  int m0 = (vbid & 127) << 6;
  int tm = threadIdx.x & 63;
  int tc = threadIdx.x >> 6;
  const float* src = lf + (size_t)bb * 64 * M_PTS;
#pragma unroll
  for (int i = 0; i < 16; i++) {
    int ch = i * 4 + tc;
    tile[ch][tm] = src[(size_t)ch * M_PTS + m0 + tm];
  }
  __syncthreads();
  float* dst = lfT + ((size_t)bb * M_PTS + m0) * 64;
#pragma unroll
  for (int i = 0; i < 16; i++) {
    int mm = i * 4 + tc;
    dst[(size_t)mm * 64 + tm] = tile[tm][mm];
  }
}

// ---------------- K1: exact KNN top-16, 2 queries per wave, 512-thr block ----------------
// R12: restored to the measured-best (512,8) config (R8: 116.4 us total for
// the full grid; accepts the VGPR-granularity spill in exchange for 32
// waves/CU — beats every no-spill variant: R7 125.0, R9 122.3, R11 121.8).
// Grid is SPLIT into two half dispatches (qbase 0 / 16384, 1024 blocks each,
// ~58 us apiece): neutral for knn (same 4-blocks/CU generations, same total
// work) but drops knn below feat in the profiler's top-5 so feat's counters
// finally become visible. Algorithm unchanged (R4-lineage): monotone prefix
// tau + dbuf staging + O(1)-sort finalize + exact rescore -> bit-identical.
__global__ void __launch_bounds__(512, 8) knn_kernel(const float4* __restrict__ pp,
                                                     const float4* __restrict__ qp,
                                                     int* __restrict__ knn_out,
                                                     int qbase) {
  __shared__ float4 spts[2][512];        // 16 KB double-buffered point stage
  __shared__ ull cbuf[16][96];           // 12 KB cand buffers (per wave x 2 q; 192 u32 view)
  const int tid = threadIdx.x;
  const int lane = tid & 63;
  const int wave = tid >> 6;                      // 0..7
  const int qa = qbase + blockIdx.x * 16 + wave * 2;   // this wave's two queries
  const int b = qa >> 13;                         // batch = global query / 8192
  const float4* pb = pp + ((size_t)b << 13);

  const float4 A4 = qp[qa];
  const float4 B4 = qp[qa + 1];
  const float axA = -2.0f * A4.x, ayA = -2.0f * A4.y, azA = -2.0f * A4.z;
  const float axB = -2.0f * B4.x, ayB = -2.0f * B4.y, azB = -2.0f * B4.z;

  int cntA = 0, cntB = 0;
  unsigned* cqA = (unsigned*)cbuf[wave * 2 + 0];
  unsigned* cqB = (unsigned*)cbuf[wave * 2 + 1];

  float mnA = 3.402823466e38f, mnB = 3.402823466e38f;
  float tauA = 0.0f, tauB = 0.0f;

  auto stage = [&](float4* dst, int s) {
    // 8 waves x 64 lanes cover the 512-pt sub-chunk with ONE ld_lds16 each
    const float4* g = pb + s * 512 + wave * 64 + lane;
    ld_lds16(g, &dst[wave * 64]);        // wave-uniform LDS base + lane*16
  };

  auto minpass = [&](const float4* sp) {
#pragma unroll
    for (int j = 0; j < 8; j++) {
      float4 p = sp[j * 64 + lane];
      mnA = fminf(mnA, __builtin_fmaf(axA, p.x, __builtin_fmaf(ayA, p.y,
                       __builtin_fmaf(azA, p.z, p.w))));
      mnB = fminf(mnB, __builtin_fmaf(axB, p.x, __builtin_fmaf(ayB, p.y,
                       __builtin_fmaf(azB, p.z, p.w))));
    }
  };

  auto collect = [&](float e, float tau, unsigned* cq, int& cnt, unsigned idx) {
    bool pred = e <= tau;
    unsigned long long mask = __ballot(pred);
    if (mask) {                           // wave-uniform; most iters skip here
      int pos = cnt + lane_prefix(mask);
      if (pred && pos < 192) cq[pos] = idx;
      cnt += __popcll(mask);
    }
  };

  auto fused = [&](const float4* sp, unsigned base) {
#pragma unroll
    for (int j = 0; j < 8; j++) {
      float4 p = sp[j * 64 + lane];
      float ea = __builtin_fmaf(axA, p.x, __builtin_fmaf(ayA, p.y,
                 __builtin_fmaf(azA, p.z, p.w)));
      float eb = __builtin_fmaf(axB, p.x, __builtin_fmaf(ayB, p.y,
                 __builtin_fmaf(azB, p.z, p.w)));
      mnA = fminf(mnA, ea);
      mnB = fminf(mnB, eb);
      unsigned idx = base + j * 64 + lane;
      collect(ea, tauA, cqA, cntA, idx);
      collect(eb, tauB, cqB, cntB, idx);
    }
  };

  // ---- prologue: seed tau on first 1024 pts (two-pass over sc0/sc1) ----
  stage(spts[0], 0);
  __syncthreads();                       // sc0 visible
  stage(spts[1], 1);                     // in flight during minpass(sc0)
  minpass(spts[0]);
  __syncthreads();                       // sc1 visible
  minpass(spts[1]);
  tauA = tau16(mnA) + 0.01f;             // margin >> fma-vs-exact divergence
  tauB = tau16(mnB) + 0.01f;
  fused(spts[0], 0);
  fused(spts[1], 512);
  __syncthreads();                       // all waves done reading sc0/sc1
  stage(spts[0], 2);
  __syncthreads();                       // sc2 visible (single true stall)

  // ---- steady state: stage next sub-chunk, compute current, barrier ----
  for (int s = 2; s < 16; ++s) {
    if (s < 15) stage(spts[(s + 1) & 1], s + 1);
    fused(spts[s & 1], (unsigned)(s * 512));
    if (s == 3 || s == 7 || s == 11) {   // tighten tau at 2048/4096/6144 prefixes
      tauA = fminf(tauA, tau16(mnA) + 0.01f);
      tauB = fminf(tauB, tau16(mnB) + 0.01f);
    }
    __syncthreads();                     // drains vmcnt -> next buffer visible;
  }                                      // also protects the swap

  auto finalize = [&](ull* cb, int cnt, int gq,
                      float qx, float qy, float qz, float q2) {
    unsigned* cu = (unsigned*)cb;
    int E = cnt < 192 ? cnt : 192;            // E >= 16 guaranteed by prologue tau
    unsigned i0 = (lane < E) ? cu[lane] : 0u;
    unsigned i1 = (lane + 64 < E) ? cu[lane + 64] : 0u;
    unsigned i2 = (lane + 128 < E) ? cu[lane + 128] : 0u;
    float4 p0 = pb[i0];                       // parallel L2-hit loads
    float4 p1 = pb[i1];
    float4 p2 = pb[i2];
    ull k0 = ~0ull, k1 = ~0ull, k2 = ~0ull;
    if (lane < E)
      k0 = ((ull)flipf(d2_exact(qx, qy, qz, q2, p0)) << 32) | i0;
    if (lane + 64 < E)
      k1 = ((ull)flipf(d2_exact(qx, qy, qz, q2, p1)) << 32) | i1;
    if (lane + 128 < E)
      k2 = ((ull)flipf(d2_exact(qx, qy, qz, q2, p2)) << 32) | i2;
    // lane-min, then T = 16th-smallest lane-min (valid: E>=16 -> lanes 0..15
    // all hold a real k0). Every true top-16 key <= T; keys <= T live only in
    // the 16 lanes whose lane-min <= T -> at most 48 survivors.
    ull ml = k0 < k1 ? k0 : k1;
    if (k2 < ml) ml = k2;
    ull T = __shfl(bsort64(ml, lane), 15);
    // ballot-compact survivors into cb (u64 view; cu reads already consumed)
    int c2 = 0;
    {
      bool pr = k0 <= T; ull m = __ballot(pr);
      int pos = c2 + lane_prefix(m);
      if (pr) cb[pos] = k0;
      c2 += __popcll(m);
    }
    {
      bool pr = k1 <= T; ull m = __ballot(pr);
      int pos = c2 + lane_prefix(m);
      if (pr) cb[pos] = k1;
      c2 += __popcll(m);
    }
    {
      bool pr = k2 <= T; ull m = __ballot(pr);
      int pos = c2 + lane_prefix(m);
      if (pr) cb[pos] = k2;
      c2 += __popcll(m);
    }
    // wave-local RAW: lgkmcnt ordering suffices, no barrier
    ull kk = (lane < c2) ? cb[lane] : ~0ull;
    ull fin = bsort64(kk, lane);
    if (lane < 16) knn_out[(size_t)gq * 16 + lane] = (int)(unsigned)fin;
  };

  finalize(cbuf[wave * 2 + 0], cntA, qa,     A4.x, A4.y, A4.z, A4.w);
  finalize(cbuf[wave * 2 + 1], cntB, qa + 1, B4.x, B4.y, B4.z, B4.w);
}

// ---------------- K2: fused feature pipeline, 32 queries per 512-thr block ----------------
// lane = channel; w1 transposed in LDS (conflict-free reads). R12: unchanged
// from R11 (current best residual). With knn split below feat's duration,
// this kernel's counters appear in the profile for the first time.
__global__ void __launch_bounds__(512) feat_kernel(
    const float4* __restrict__ pp, const float4* __restrict__ qp,
    const int* __restrict__ knn, const float* __restrict__ lfT,
    const float* __restrict__ w0, const float* __restrict__ b0,
    const float* __restrict__ g0, const float* __restrict__ be0,
    const float* __restrict__ m0, const float* __restrict__ v0,
    const float* __restrict__ w1, const float* __restrict__ b1,
    const float* __restrict__ g1, const float* __restrict__ be1,
    const float* __restrict__ m1, const float* __restrict__ v1,
    const float* __restrict__ w2, const float* __restrict__ b2,
    float* __restrict__ out) {
  __shared__ float w1T[64][65];        // 16.6 KB transposed w1 (pad kills conflicts)
  __shared__ float4 relbuf[8][16];     // 2 KB
  __shared__ float4 f0v[8][64];        // 8 KB
  __shared__ float outbuf[64][33];     // 8.45 KB, +1 pad breaks bank conflicts
  const int tid = threadIdx.x;
  const int lane = tid & 63;
  const int wave = tid >> 6;           // 0..7
  const int gq0 = blockIdx.x * 32;
  const int b = gq0 >> 13;

  // cooperative transpose of w1 (64x64) into LDS: 512 threads x 2 float4
  {
    const float4* w1f4 = (const float4*)w1;
#pragma unroll
    for (int k = 0; k < 2; k++) {
      int linear4 = tid + k * 512;           // float4 index in [0,1024)
      int c = linear4 >> 4;                  // row (out channel)
      int c2 = (linear4 & 15) * 4;           // col (in channel)
      float4 t = w1f4[linear4];
      w1T[c2 + 0][c] = t.x;
      w1T[c2 + 1][c] = t.y;
      w1T[c2 + 2][c] = t.z;
      w1T[c2 + 3][c] = t.w;
    }
  }

  // BN folds (inline; fp order matches R0's fold_kernel)
  const float inv0 = g0[lane] / sqrtf(v0[lane] + 1e-5f);
  const float w00 = w0[lane * 3 + 0] * inv0;
  const float w01 = w0[lane * 3 + 1] * inv0;
  const float w02 = w0[lane * 3 + 2] * inv0;
  const float bb0 = (b0[lane] - m0[lane]) * inv0 + be0[lane];
  const float inv1 = g1[lane] / sqrtf(v1[lane] + 1e-5f);
  const float bb1 = (b1[lane] - m1[lane]) * inv1 + be1[lane];

  const float w2a = w2[lane], w2b = w2[64 + lane];
  const float bias2 = b2[0];
  const float4* pb = pp + ((size_t)b << 13);
  const float* lfb = lfT + (((size_t)b << 13)) * 64;

  __syncthreads();                       // w1T visible to all waves

  for (int qi = 0; qi < 4; qi++) {
    const int gq = gq0 + wave * 4 + qi;
    const float4 q4 = qp[gq];
    int nk = knn[(size_t)gq * 16 + (lane & 15)];
    float4 pk = pb[nk];
    // issue the lfb gathers NOW (they only need nk); latency hides under
    // conv0 + matvec below
    int i0 = __shfl(nk, 0), i1 = __shfl(nk, 1), i2 = __shfl(nk, 2), i3 = __shfl(nk, 3);
    float p0 = lfb[(size_t)i0 * 64 + lane];
    float p1 = lfb[(size_t)i1 * 64 + lane];
    float p2 = lfb[(size_t)i2 * 64 + lane];
    float p3 = lfb[(size_t)i3 * 64 + lane];

    if (lane < 16)
      relbuf[wave][lane] = make_float4(pk.x - q4.x, pk.y - q4.y, pk.z - q4.z, 0.0f);
    // wave-local RAW: lgkmcnt ordering suffices, no barrier

    float g = 0.0f, f0 = 0, f1 = 0, f2 = 0, f3 = 0;
#pragma unroll
    for (int k = 0; k < 16; k++) {
      float4 r = relbuf[wave][k];
      float y = fmaxf(0.0f, w00 * r.x + w01 * r.y + w02 * r.z + bb0);
      g = fmaxf(g, y);
      if (k == 0) f0 = y; else if (k == 1) f1 = y;
      else if (k == 2) f2 = y; else if (k == 3) f3 = y;
    }
    f0v[wave][lane] = make_float4(f0, f1, f2, f3);

    float a0 = 0, a1 = 0, a2 = 0, a3 = 0;
#pragma unroll
    for (int c2 = 0; c2 < 64; c2++) {
      float w = w1T[c2][lane];           // LDS, lane-consecutive: conflict-free
      float4 fb = f0v[wave][c2];         // LDS broadcast (same addr all lanes)
      a0 = fmaf(w, fb.x, a0); a1 = fmaf(w, fb.y, a1);
      a2 = fmaf(w, fb.z, a2); a3 = fmaf(w, fb.w, a3);
    }
    float r0 = fmaxf(0.0f, fmaf(a0, inv1, bb1));
    float r1 = fmaxf(0.0f, fmaf(a1, inv1, bb1));
    float r2 = fmaxf(0.0f, fmaf(a2, inv1, bb1));
    float r3 = fmaxf(0.0f, fmaf(a3, inv1, bb1));

    float s0 = w2a * r0, s1 = w2a * r1, s2 = w2a * r2, s3 = w2a * r3, tg = w2b * g;
#pragma unroll
    for (int j = 1; j < 64; j <<= 1) {
      s0 += __shfl_xor(s0, j);
      s1 += __shfl_xor(s1, j);
      s2 += __shfl_xor(s2, j);
      s3 += __shfl_xor(s3, j);
      tg += __shfl_xor(tg, j);
    }
    float wk0 = 1.0f / (1.0f + __expf(-(s0 + tg + bias2)));
    float wk1 = 1.0f / (1.0f + __expf(-(s1 + tg + bias2)));
    float wk2 = 1.0f / (1.0f + __expf(-(s2 + tg + bias2)));
    float wk3 = 1.0f / (1.0f + __expf(-(s3 + tg + bias2)));

    float oc = ((1.0f - wk0) * r0 + wk0 * p0)
             + ((1.0f - wk1) * r1 + wk1 * p1)
             + ((1.0f - wk2) * r2 + wk2 * p2)
             + ((1.0f - wk3) * r3 + wk3 * p3);
    outbuf[lane][wave * 4 + qi] = oc;
  }
  __syncthreads();

  // coalesced output: thread t -> channel c = t>>3, 8 query-groups via float4
  int c = tid >> 3, j = tid & 7;
  float4 o4 = make_float4(outbuf[c][j * 4 + 0], outbuf[c][j * 4 + 1],
                          outbuf[c][j * 4 + 2], outbuf[c][j * 4 + 3]);
  *(float4*)(out + (((size_t)(b * 64 + c)) << 13) + (gq0 & (N_QRY - 1)) + j * 4) = o4;
}

extern "C" void kernel_launch(void* const* d_in, const int* in_sizes, int n_in,
                              void* d_out, int out_size, void* d_ws, size_t ws_size,
                              hipStream_t stream) {
  (void)in_sizes; (void)n_in; (void)out_size; (void)ws_size;
  const float* original_pts = (const float*)d_in[0];
  const float* query_pts   = (const float*)d_in[1];
  const float* local_feat  = (const float*)d_in[2];
  const float* w0 = (const float*)d_in[3];
  const float* b0 = (const float*)d_in[4];
  const float* g0 = (const float*)d_in[5];
  const float* be0 = (const float*)d_in[6];
  const float* m0 = (const float*)d_in[7];
  const float* v0 = (const float*)d_in[8];
  const float* w1 = (const float*)d_in[9];
  const float* b1 = (const float*)d_in[10];
  const float* g1 = (const float*)d_in[11];
  const float* be1 = (const float*)d_in[12];
  const float* m1 = (const float*)d_in[13];
  const float* v1 = (const float*)d_in[14];
  const float* w2 = (const float*)d_in[15];
  const float* b2 = (const float*)d_in[16];
  float* out = (float*)d_out;

  // workspace layout (16B aligned), total ~11.5 MB
  char* ws = (char*)d_ws;
  float4* pp  = (float4*)(ws);                 // 512 KB
  float4* qp  = (float4*)(ws + 524288);        // 512 KB
  float*  lfT = (float*)(ws + 1048576);        // 8 MB
  int*    knn = (int*)(ws + 9437184);          // 2 MB

  prep_kernel<<<768, 256, 0, stream>>>(original_pts, query_pts, local_feat,
                                       pp, qp, lfT);
  knn_kernel<<<1024, 512, 0, stream>>>(pp, qp, knn, 0);
  knn_kernel<<<1024, 512, 0, stream>>>(pp, qp, knn, 16384);
  feat_kernel<<<1024, 512, 0, stream>>>(pp, qp, knn, lfT,
                                        w0, b0, g0, be0, m0, v0,
                                        w1, b1, g1, be1, m1, v1,
                                        w2, b2, out);
}

// Round 13
// 245.043 us; speedup vs baseline: 1.0413x; 1.0413x over previous
//
#include <hip/hip_runtime.h>
#include <cstdint>

#define M_PTS 8192
#define N_QRY 8192
#define BATCH 4

typedef unsigned long long ull;

// ---------------- helpers ----------------
__device__ __forceinline__ float d2_exact(float qx, float qy, float qz, float q2, float4 p) {
#pragma clang fp contract(off)
  float dot = (qx * p.x + qy * p.y) + qz * p.z;   // reference op order, no fma
  return (q2 + p.w) - 2.0f * dot;
}

__device__ __forceinline__ unsigned flipf(float d) {
  unsigned u = __float_as_uint(d);
  return u ^ ((unsigned)((int)u >> 31) | 0x80000000u);   // order-preserving float->uint
}

__device__ __forceinline__ int lane_prefix(unsigned long long m) {
  return __builtin_amdgcn_mbcnt_hi((unsigned)(m >> 32),
         __builtin_amdgcn_mbcnt_lo((unsigned)m, 0));
}

__device__ __forceinline__ void ld_lds16(const float4* g, float4* l) {
  __builtin_amdgcn_global_load_lds((const __attribute__((address_space(1))) void*)g,
                                   (__attribute__((address_space(3))) void*)l, 16, 0, 0);
}

// Upper bound on the 16th-smallest of the 64 per-lane mins, via ballot bisection.
// Invariant: count(mn <= hi) >= 16 holds from init (hi = wave max -> 64). 10 steps
// give resolution (hi0-lo0)/1024; looseness only ADDS candidates, never drops one.
__device__ __forceinline__ float tau16(float mn) {
  float lo = mn, hi = mn;
#pragma unroll
  for (int j = 1; j < 64; j <<= 1) {
    lo = fminf(lo, __shfl_xor(lo, j));
    hi = fmaxf(hi, __shfl_xor(hi, j));
  }
#pragma unroll
  for (int it = 0; it < 10; it++) {
    float mid = 0.5f * (lo + hi);
    int cnt = __popcll(__ballot(mn <= mid));
    if (cnt >= 16) hi = mid; else lo = mid;   // wave-uniform
  }
  return hi;
}

// Full 64-lane ascending bitonic sort of u64 keys; lane i ends with the i-th
// smallest. Same network/orientation as the R0-verified rank16.
__device__ __forceinline__ ull bsort64(ull v, int lane) {
#pragma unroll
  for (int k = 2; k <= 64; k <<= 1) {
#pragma unroll
    for (int j = k >> 1; j >= 1; j >>= 1) {
      ull o = __shfl_xor(v, j);
      bool keepmin = (((lane & k) == 0) == ((lane & j) == 0));
      ull lo = v < o ? v : o;
      ull hi = v < o ? o : v;
      v = keepmin ? lo : hi;
    }
  }
  return v;
}

// ---------------- K0: fused prep (pack orig + pack query + transpose lf) ----------
// blocks [0,128): pack original_pts -> pp ; [128,256): pack query_pts -> qp ;
// [256,768): transpose local_feat (B,64,M) -> (B,M,64).
__global__ void prep_kernel(const float* __restrict__ original_pts,
                            const float* __restrict__ query_pts,
                            const float* __restrict__ lf,
                            float4* __restrict__ pp, float4* __restrict__ qp,
                            float* __restrict__ lfT) {
#pragma clang fp contract(off)
  const int bid = blockIdx.x;
  if (bid < 256) {
    const float* src = (bid < 128) ? original_pts : query_pts;
    float4* dst = (bid < 128) ? pp : qp;
    int i = (bid & 127) * 256 + threadIdx.x;     // < 32768
    int b = i >> 13, m = i & (M_PTS - 1);
    const float* s = src + (size_t)b * 3 * M_PTS;
    float x = s[m], y = s[M_PTS + m], z = s[2 * M_PTS + m];
    float ss = (x * x + y * y) + z * z;   // matches jnp.sum(pts**2, axis=1) order
    dst[i] = make_float4(x, y, z, ss);
    return;
  }
  __shared__ float tile[64][65];
  int vbid = bid - 256;
  int bb = vbid >> 7;
  int m0 = (vbid & 127) << 6;
  int tm = threadIdx.x & 63;
  int tc = threadIdx.x >> 6;
  const float* src = lf + (size_t)bb * 64 * M_PTS;
#pragma unroll
  for (int i = 0; i < 16; i++) {
    int ch = i * 4 + tc;
    tile[ch][tm] = src[(size_t)ch * M_PTS + m0 + tm];
  }
  __syncthreads();
  float* dst = lfT + ((size_t)bb * M_PTS + m0) * 64;
#pragma unroll
  for (int i = 0; i < 16; i++) {
    int mm = i * 4 + tc;
    dst[(size_t)mm * 64 + tm] = tile[tm][mm];
  }
}

// ---------------- K1: FUSED knn + feat, 16 queries per 512-thr block ----------------
// R13: knn (R4-lineage, bit-identical) and feat (R8/R11 body) fused into one
// kernel. R12 measured: knn halves 63 us each, feat < 63 us, and ~60 us of
// the 255 us total was inter-dispatch overhead (~15 us/launch). Fusion:
// (a) selected top-16 indices stay in LDS (sknn) — no 2 MB global round-trip;
// (b) launches 4 -> 2 (~30 us of gaps gone); (c) no global barrier between
// knn and feat — feat of generation-1 blocks overlaps knn of generation-2.
// LDS phases OVERLAY in one buffer (knn 28 KB, feat 31.2 KB, union + sknn =
// 32.3 KB -> still 4 blocks/CU). Double-buffer selected by pointer arithmetic
// (no runtime-indexed pointer array -> no scratch). __launch_bounds__(512)
// natural regs: a forced 64-cap would spill the feat phase.
__global__ void __launch_bounds__(512) fused_kernel(
    const float4* __restrict__ pp, const float4* __restrict__ qp,
    const float* __restrict__ lfT,
    const float* __restrict__ w0, const float* __restrict__ b0,
    const float* __restrict__ g0, const float* __restrict__ be0,
    const float* __restrict__ m0, const float* __restrict__ v0,
    const float* __restrict__ w1, const float* __restrict__ b1,
    const float* __restrict__ g1, const float* __restrict__ be1,
    const float* __restrict__ m1, const float* __restrict__ v1,
    const float* __restrict__ w2, const float* __restrict__ b2,
    float* __restrict__ out) {
  // ---- overlaid LDS: knn {spts 16K @0, cbuf 12K @16384} / feat {w1T 16.64K
  // @0, relbuf 2K @16640, f0v 8K @18688, outbuf 4.35K @26880} ----
  __shared__ __align__(16) char smem[31232];
  __shared__ int sknn[16][16];           // persists across the phase boundary
  const int tid = threadIdx.x;
  const int lane = tid & 63;
  const int wave = tid >> 6;                      // 0..7
  const int gq0 = blockIdx.x * 16;                // block's 16 queries
  const int qa = gq0 + wave * 2;                  // this wave's two queries
  const int b = qa >> 13;                         // 512 blocks per batch
  const float4* pb = pp + ((size_t)b << 13);

  // ================= PHASE 1: exact KNN top-16 (R4-lineage) =================
  {
    ull (*cbuf)[96] = (ull(*)[96])(smem + 16384);

    const float4 A4 = qp[qa];
    const float4 B4 = qp[qa + 1];
    const float axA = -2.0f * A4.x, ayA = -2.0f * A4.y, azA = -2.0f * A4.z;
    const float axB = -2.0f * B4.x, ayB = -2.0f * B4.y, azB = -2.0f * B4.z;

    int cntA = 0, cntB = 0;
    unsigned* cqA = (unsigned*)cbuf[wave * 2 + 0];
    unsigned* cqB = (unsigned*)cbuf[wave * 2 + 1];

    float mnA = 3.402823466e38f, mnB = 3.402823466e38f;
    float tauA = 0.0f, tauB = 0.0f;

    auto bufp = [&](int d) -> float4* {           // pointer ARITHMETIC, not
      return (float4*)(smem + ((size_t)d << 13)); // runtime-indexed array
    };

    auto stage = [&](int d, int s) {
      // 8 waves x 64 lanes cover the 512-pt sub-chunk with ONE ld_lds16 each
      const float4* g = pb + s * 512 + wave * 64 + lane;
      ld_lds16(g, bufp(d) + wave * 64);   // wave-uniform LDS base + lane*16
    };

    auto minpass = [&](const float4* sp) {
#pragma unroll
      for (int j = 0; j < 8; j++) {
        float4 p = sp[j * 64 + lane];
        mnA = fminf(mnA, __builtin_fmaf(axA, p.x, __builtin_fmaf(ayA, p.y,
                         __builtin_fmaf(azA, p.z, p.w))));
        mnB = fminf(mnB, __builtin_fmaf(axB, p.x, __builtin_fmaf(ayB, p.y,
                         __builtin_fmaf(azB, p.z, p.w))));
      }
    };

    auto collect = [&](float e, float tau, unsigned* cq, int& cnt, unsigned idx) {
      bool pred = e <= tau;
      unsigned long long mask = __ballot(pred);
      if (mask) {                         // wave-uniform; most iters skip here
        int pos = cnt + lane_prefix(mask);
        if (pred && pos < 192) cq[pos] = idx;
        cnt += __popcll(mask);
      }
    };

    auto fused = [&](const float4* sp, unsigned base) {
#pragma unroll
      for (int j = 0; j < 8; j++) {
        float4 p = sp[j * 64 + lane];
        float ea = __builtin_fmaf(axA, p.x, __builtin_fmaf(ayA, p.y,
                   __builtin_fmaf(azA, p.z, p.w)));
        float eb = __builtin_fmaf(axB, p.x, __builtin_fmaf(ayB, p.y,
                   __builtin_fmaf(azB, p.z, p.w)));
        mnA = fminf(mnA, ea);
        mnB = fminf(mnB, eb);
        unsigned idx = base + j * 64 + lane;
        collect(ea, tauA, cqA, cntA, idx);
        collect(eb, tauB, cqB, cntB, idx);
      }
    };

    // ---- prologue: seed tau on first 1024 pts (two-pass over sc0/sc1) ----
    stage(0, 0);
    __syncthreads();                     // sc0 visible
    stage(1, 1);                         // in flight during minpass(sc0)
    minpass(bufp(0));
    __syncthreads();                     // sc1 visible
    minpass(bufp(1));
    tauA = tau16(mnA) + 0.01f;           // margin >> fma-vs-exact divergence
    tauB = tau16(mnB) + 0.01f;
    fused(bufp(0), 0);
    fused(bufp(1), 512);
    __syncthreads();                     // all waves done reading sc0/sc1
    stage(0, 2);
    __syncthreads();                     // sc2 visible (single true stall)

    // ---- steady state: stage next sub-chunk, compute current, barrier ----
    for (int s = 2; s < 16; ++s) {
      if (s < 15) stage((s + 1) & 1, s + 1);
      fused(bufp(s & 1), (unsigned)(s * 512));
      if (s == 3 || s == 7 || s == 11) { // tighten tau at 2048/4096/6144 prefixes
        tauA = fminf(tauA, tau16(mnA) + 0.01f);
        tauB = fminf(tauB, tau16(mnB) + 0.01f);
      }
      __syncthreads();                   // drains vmcnt -> next buffer visible;
    }                                    // also protects the swap

    auto finalize = [&](ull* cb, int cnt, int* srow,
                        float qx, float qy, float qz, float q2) {
      unsigned* cu = (unsigned*)cb;
      int E = cnt < 192 ? cnt : 192;          // E >= 16 guaranteed by prologue tau
      unsigned i0 = (lane < E) ? cu[lane] : 0u;
      unsigned i1 = (lane + 64 < E) ? cu[lane + 64] : 0u;
      unsigned i2 = (lane + 128 < E) ? cu[lane + 128] : 0u;
      float4 p0 = pb[i0];                     // parallel L2-hit loads
      float4 p1 = pb[i1];
      float4 p2 = pb[i2];
      ull k0 = ~0ull, k1 = ~0ull, k2 = ~0ull;
      if (lane < E)
        k0 = ((ull)flipf(d2_exact(qx, qy, qz, q2, p0)) << 32) | i0;
      if (lane + 64 < E)
        k1 = ((ull)flipf(d2_exact(qx, qy, qz, q2, p1)) << 32) | i1;
      if (lane + 128 < E)
        k2 = ((ull)flipf(d2_exact(qx, qy, qz, q2, p2)) << 32) | i2;
      // lane-min, then T = 16th-smallest lane-min (E>=16 -> lanes 0..15 all
      // hold a real k0). Every true top-16 key <= T; keys <= T live only in
      // the 16 lanes whose lane-min <= T -> at most 48 survivors.
      ull ml = k0 < k1 ? k0 : k1;
      if (k2 < ml) ml = k2;
      ull T = __shfl(bsort64(ml, lane), 15);
      int c2 = 0;
      {
        bool pr = k0 <= T; ull m = __ballot(pr);
        int pos = c2 + lane_prefix(m);
        if (pr) cb[pos] = k0;
        c2 += __popcll(m);
      }
      {
        bool pr = k1 <= T; ull m = __ballot(pr);
        int pos = c2 + lane_prefix(m);
        if (pr) cb[pos] = k1;
        c2 += __popcll(m);
      }
      {
        bool pr = k2 <= T; ull m = __ballot(pr);
        int pos = c2 + lane_prefix(m);
        if (pr) cb[pos] = k2;
        c2 += __popcll(m);
      }
      // wave-local RAW: lgkmcnt ordering suffices, no barrier
      ull kk = (lane < c2) ? cb[lane] : ~0ull;
      ull fin = bsort64(kk, lane);
      if (lane < 16) srow[lane] = (int)(unsigned)fin;   // -> LDS, not global
    };

    finalize(cbuf[wave * 2 + 0], cntA, sknn[wave * 2 + 0], A4.x, A4.y, A4.z, A4.w);
    finalize(cbuf[wave * 2 + 1], cntB, sknn[wave * 2 + 1], B4.x, B4.y, B4.z, B4.w);
  }

  __syncthreads();                       // all finalize done; smem reusable

  // ================= PHASE 2: feature pipeline (R8/R11 body) =================
  float (*w1T)[65]    = (float(*)[65])smem;
  float4 (*relbuf)[16] = (float4(*)[16])(smem + 16640);
  float4 (*f0v)[64]   = (float4(*)[64])(smem + 18688);
  float (*outbuf)[17] = (float(*)[17])(smem + 26880);

  // cooperative transpose of w1 (64x64) into LDS: 512 threads x 2 float4
  {
    const float4* w1f4 = (const float4*)w1;
#pragma unroll
    for (int k = 0; k < 2; k++) {
      int linear4 = tid + k * 512;           // float4 index in [0,1024)
      int c = linear4 >> 4;                  // row (out channel)
      int c2 = (linear4 & 15) * 4;           // col (in channel)
      float4 t = w1f4[linear4];
      w1T[c2 + 0][c] = t.x;
      w1T[c2 + 1][c] = t.y;
      w1T[c2 + 2][c] = t.z;
      w1T[c2 + 3][c] = t.w;
    }
  }

  // BN folds (inline; fp order matches R0's fold_kernel)
  const float inv0 = g0[lane] / sqrtf(v0[lane] + 1e-5f);
  const float w00 = w0[lane * 3 + 0] * inv0;
  const float w01 = w0[lane * 3 + 1] * inv0;
  const float w02 = w0[lane * 3 + 2] * inv0;
  const float bb0 = (b0[lane] - m0[lane]) * inv0 + be0[lane];
  const float inv1 = g1[lane] / sqrtf(v1[lane] + 1e-5f);
  const float bb1 = (b1[lane] - m1[lane]) * inv1 + be1[lane];

  const float w2a = w2[lane], w2b = w2[64 + lane];
  const float bias2 = b2[0];
  const float* lfb = lfT + (((size_t)b << 13)) * 64;

  __syncthreads();                       // w1T visible to all waves

  for (int qi = 0; qi < 2; qi++) {
    const int gq = qa + qi;
    const float4 q4 = qp[gq];
    int nk = sknn[wave * 2 + qi][lane & 15];   // LDS broadcast read
    float4 pk = pb[nk];
    // issue the lfb gathers NOW (they only need nk); latency hides under
    // conv0 + matvec below
    int i0 = __shfl(nk, 0), i1 = __shfl(nk, 1), i2 = __shfl(nk, 2), i3 = __shfl(nk, 3);
    float p0 = lfb[(size_t)i0 * 64 + lane];
    float p1 = lfb[(size_t)i1 * 64 + lane];
    float p2 = lfb[(size_t)i2 * 64 + lane];
    float p3 = lfb[(size_t)i3 * 64 + lane];

    if (lane < 16)
      relbuf[wave][lane] = make_float4(pk.x - q4.x, pk.y - q4.y, pk.z - q4.z, 0.0f);
    // wave-local RAW: lgkmcnt ordering suffices, no barrier

    float g = 0.0f, f0 = 0, f1 = 0, f2 = 0, f3 = 0;
#pragma unroll
    for (int k = 0; k < 16; k++) {
      float4 r = relbuf[wave][k];
      float y = fmaxf(0.0f, w00 * r.x + w01 * r.y + w02 * r.z + bb0);
      g = fmaxf(g, y);
      if (k == 0) f0 = y; else if (k == 1) f1 = y;
      else if (k == 2) f2 = y; else if (k == 3) f3 = y;
    }
    f0v[wave][lane] = make_float4(f0, f1, f2, f3);

    float a0 = 0, a1 = 0, a2 = 0, a3 = 0;
#pragma unroll
    for (int c2 = 0; c2 < 64; c2++) {
      float w = w1T[c2][lane];           // LDS, lane-consecutive: conflict-free
      float4 fb = f0v[wave][c2];         // LDS broadcast (same addr all lanes)
      a0 = fmaf(w, fb.x, a0); a1 = fmaf(w, fb.y, a1);
      a2 = fmaf(w, fb.z, a2); a3 = fmaf(w, fb.w, a3);
    }
    float r0 = fmaxf(0.0f, fmaf(a0, inv1, bb1));
    float r1 = fmaxf(0.0f, fmaf(a1, inv1, bb1));
    float r2 = fmaxf(0.0f, fmaf(a2, inv1, bb1));
    float r3 = fmaxf(0.0f, fmaf(a3, inv1, bb1));

    float s0 = w2a * r0, s1 = w2a * r1, s2 = w2a * r2, s3 = w2a * r3, tg = w2b * g;
#pragma unroll
    for (int j = 1; j < 64; j <<= 1) {
      s0 += __shfl_xor(s0, j);
      s1 += __shfl_xor(s1, j);
      s2 += __shfl_xor(s2, j);
      s3 += __shfl_xor(s3, j);
      tg += __shfl_xor(tg, j);
    }
    float wk0 = 1.0f / (1.0f + __expf(-(s0 + tg + bias2)));
    float wk1 = 1.0f / (1.0f + __expf(-(s1 + tg + bias2)));
    float wk2 = 1.0f / (1.0f + __expf(-(s2 + tg + bias2)));
    float wk3 = 1.0f / (1.0f + __expf(-(s3 + tg + bias2)));

    float oc = ((1.0f - wk0) * r0 + wk0 * p0)
             + ((1.0f - wk1) * r1 + wk1 * p1)
             + ((1.0f - wk2) * r2 + wk2 * p2)
             + ((1.0f - wk3) * r3 + wk3 * p3);
    outbuf[lane][wave * 2 + qi] = oc;
  }
  __syncthreads();

  // coalesced output: thread t<256 -> channel c = t>>2, 4 queries via float4
  if (tid < 256) {
    int c = tid >> 2, j = tid & 3;
    float4 o4 = make_float4(outbuf[c][j * 4 + 0], outbuf[c][j * 4 + 1],
                            outbuf[c][j * 4 + 2], outbuf[c][j * 4 + 3]);
    *(float4*)(out + (((size_t)(b * 64 + c)) << 13) + (gq0 & (N_QRY - 1)) + j * 4) = o4;
  }
}

extern "C" void kernel_launch(void* const* d_in, const int* in_sizes, int n_in,
                              void* d_out, int out_size, void* d_ws, size_t ws_size,
                              hipStream_t stream) {
  (void)in_sizes; (void)n_in; (void)out_size; (void)ws_size;
  const float* original_pts = (const float*)d_in[0];
  const float* query_pts   = (const float*)d_in[1];
  const float* local_feat  = (const float*)d_in[2];
  const float* w0 = (const float*)d_in[3];
  const float* b0 = (const float*)d_in[4];
  const float* g0 = (const float*)d_in[5];
  const float* be0 = (const float*)d_in[6];
  const float* m0 = (const float*)d_in[7];
  const float* v0 = (const float*)d_in[8];
  const float* w1 = (const float*)d_in[9];
  const float* b1 = (const float*)d_in[10];
  const float* g1 = (const float*)d_in[11];
  const float* be1 = (const float*)d_in[12];
  const float* m1 = (const float*)d_in[13];
  const float* v1 = (const float*)d_in[14];
  const float* w2 = (const float*)d_in[15];
  const float* b2 = (const float*)d_in[16];
  float* out = (float*)d_out;

  // workspace layout (16B aligned): pp 512K, qp 512K, lfT 8M
  char* ws = (char*)d_ws;
  float4* pp  = (float4*)(ws);                 // 512 KB
  float4* qp  = (float4*)(ws + 524288);        // 512 KB
  float*  lfT = (float*)(ws + 1048576);        // 8 MB

  prep_kernel<<<768, 256, 0, stream>>>(original_pts, query_pts, local_feat,
                                       pp, qp, lfT);
  fused_kernel<<<2048, 512, 0, stream>>>(pp, qp, lfT,
                                         w0, b0, g0, be0, m0, v0,
                                         w1, b1, g1, be1, m1, v1,
                                         w2, b2, out);
}